// Round 8
// baseline (148.178 us; speedup 1.0000x reference)
//
#include <hip/hip_runtime.h>

// KAN layer, R11: FUSED A-generation. Records padded to 32 slots so 1 j == one
// MFMA K=32 step: [basis 0..19, neg, pos, 10 zeros] (A-side, generated on the
// fly from x inside the gemm) . [sw*sc 0..19, bw*pw, bw, 10 zeros] (Ct32,
// materialized by prep_c32, 16.8 MB). The 46.1 MB A matrix and prep_A's
// ~30 us are DELETED. Rationale (R10 post-mortem): four different gemm
// schedules all hit a ~40 us floor with every pipe <25%; rather than fight
// the floor, remove the prep kernel + A round-trip that sit in front of it.
// Fused kernel: grid (8,2,16)=256 blocks (1/CU), 512 thr, 8 waves (2m x 4n),
// wave-tile 128x64, acc[8][4] — R10's verified fragment/epilogue skeleton.
// Per phase (= 2 j, K=64): stage Bs[p+1] via global_load_lds (pre-swizzled
// source, rule-21 involution), generate 512 A-records (one per thread:
// bspline5 + swizzled ds_write, row-XOR (r&7) on 128-B rows = conflict-free
// b128), 2x32 MFMA. LDS = 32K x-tile + 2x32K As + 2x32K Bs = 160 KiB exactly.
// ws: Ct32 16.8 MB + partials16 67.1 MB = 83.9 MB.

typedef _Float16 half_t;
typedef __attribute__((ext_vector_type(8))) _Float16 half8;
typedef __attribute__((ext_vector_type(4))) float floatx4;

#define B_DIM   2048
#define J_DIM   512
#define O_DIM   512
#define SLOT32  32
#define KT32    (J_DIM * SLOT32)     // 16384
#define BM      256
#define BN      256
#define KSPLIT  16                   // j-slice = 32 j = 16 phases of 2 j
#define NPH     16

// ---------------------------------------------------------------------------
// Quartic B-spline local basis, uniform knots g_i = -1.5 + i*(3.125/24).
// (Reference quirk: linspace(-1.5, 1.625, 25) -> spacing 3.125/24, NOT 0.125.)
__device__ __forceinline__ void bspline5(float xc, int& k0, float Nv[5]) {
    const float invS = 7.68f;              // 24/3.125 (exact ratio)
    float u = (xc + 1.5f) * invS;          // knot units
    int m = (int)u;
    m = min(max(m, 3), 19);
    k0 = m - 4;
    Nv[0] = 1.f; Nv[1] = 0.f; Nv[2] = 0.f; Nv[3] = 0.f; Nv[4] = 0.f;
#pragma unroll
    for (int d = 1; d <= 4; ++d) {
        float nw[5];
        float inv_d = 1.0f / (float)d;
#pragma unroll
        for (int r = 0; r < 5; ++r) {
            if (r > d) { nw[r] = 0.f; continue; }
            float kk = (float)(m - d + r);
            float acc = 0.f;
            if (r >= 1) acc += (u - kk) * Nv[r - 1];
            if (r < d)  acc += (kk + (float)(d + 1) - u) * Nv[r];
            nw[r] = acc * inv_d;
        }
#pragma unroll
        for (int r = 0; r < 5; ++r) Nv[r] = nw[r];
    }
}

__device__ __forceinline__ unsigned packh2(float a, float b) {
    half_t ha = (half_t)a, hb = (half_t)b;    // RTN, identical to prior rounds
    unsigned short ua = __builtin_bit_cast(unsigned short, ha);
    unsigned short ub = __builtin_bit_cast(unsigned short, hb);
    return (unsigned)ua | ((unsigned)ub << 16);
}

// ---------------------------------------------------------------------------
// prep_c32: 256 blocks x 256 thr; 2 i-rows per block; 4 records per thread,
// all in registers, 16 uint4 stores. Ct32 row = 512 j x 32 halfs (32 KB).
__global__ __launch_bounds__(256) void prep_c32(const float* __restrict__ pw,
                                                const float* __restrict__ bw,
                                                const float* __restrict__ sw,
                                                const float* __restrict__ sc,
                                                half_t* __restrict__ Ct) {
    int bid = blockIdx.x;
    int t = threadIdx.x;
    int sub = t >> 7;          // 0/1: which row of the pair
    int jq  = t & 127;         // j-quad index
    int j0  = jq * 4;

    int i = bid * 2 + sub;
    size_t ij0 = (size_t)i * J_DIM + j0;
    float4 s4 = *(const float4*)(sw + ij0);
    float4 b4 = *(const float4*)(bw + ij0);
    float4 p4 = *(const float4*)(pw + ij0);
    const float4* sp4 = (const float4*)(sc + ij0 * 20);  // 20 float4s
    unsigned u[64];
#pragma unroll
    for (int jj = 0; jj < 4; ++jj) {
        float s = ((const float*)&s4)[jj];
        float b = ((const float*)&b4)[jj];
        float p = ((const float*)&p4)[jj];
#pragma unroll
        for (int v = 0; v < 5; ++v) {                   // 20 coeffs
            float4 c4 = sp4[jj * 5 + v];
            u[jj * 16 + v * 2 + 0] = packh2(s * c4.x, s * c4.y);
            u[jj * 16 + v * 2 + 1] = packh2(s * c4.z, s * c4.w);
        }
        u[jj * 16 + 10] = packh2(b * p, b);             // slots 20,21
#pragma unroll
        for (int v = 11; v < 16; ++v) u[jj * 16 + v] = 0u;  // slots 22..31
    }
    uint4* dst = (uint4*)(Ct + (size_t)i * KT32 + (size_t)j0 * SLOT32);
#pragma unroll
    for (int v = 0; v < 16; ++v)
        dst[v] = make_uint4(u[4 * v], u[4 * v + 1], u[4 * v + 2], u[4 * v + 3]);
}

// ---------------------------------------------------------------------------
// kan_fused: grid (8,2,16) = 256 blocks (1/CU), 512 thr = 8 waves (2m x 4n).
// LDS layout (records are 32 halfs; rows of As/Bs are 64 halfs = 128 B = 8
// quads of 16 B): logical quad lq of row r stored at physical quad lq^(r&7)
// — same involution on the DMA-staged Bs (pre-swizzled SOURCE per rule 21)
// and the ds_write-generated As. Read side XORs identically.
__global__ __launch_bounds__(512, 2) void kan_fused(const float* __restrict__ x,
                                                    const half_t* __restrict__ Ct,
                                                    float* __restrict__ out) {
    __shared__ float  xt[32 * 256];        // x-tile, TRANSPOSED [col][b], 32 KB
    __shared__ half_t As[2][BM * 64];      // 2 x 32 KB
    __shared__ half_t Bs[2][BN * 64];      // 2 x 32 KB   -> 160 KiB total

    int lid = blockIdx.x + 8 * (blockIdx.y + 2 * blockIdx.z);   // 0..255
    int c8 = lid & 7;                // XCD
    int r2 = lid >> 3;
    int bz = c8 + 8 * (r2 & 1);      // z in {c8, c8+8}
    int rr2 = r2 >> 1;
    int bx = rr2 & 7;                // 8 m-blocks
    int by = rr2 >> 3;               // 2 n-blocks

    int m0 = bx * BM;
    int n0 = by * BN;
    int j0 = bz * 32;                // this block's 32-j slice

    int t = threadIdx.x;
    int w = t >> 6, l = t & 63;
    int wm = w >> 2, wn = w & 3;     // wave grid 2 x 4
    int q = l >> 4, fr = l & 15;

    const half_t* gB = Ct + (size_t)n0 * KT32 + (size_t)j0 * SLOT32;

    // Bs staging decomposition: per load, wave covers 8 rows x 8 quads (1 KB).
    int srow8 = l >> 3;                      // 0..7 row within 8-row group
    int lq    = (l & 7) ^ (srow8 & 7);       // logical quad at this lane's dest

    floatx4 acc[8][4] = {};

// 4 loads/thread/phase; dest linear (DMA), source pre-swizzled.
#define ISSUE_BS(p, buf)                                                      \
    {                                                                         \
        _Pragma("unroll")                                                     \
        for (int s = 0; s < 4; ++s) {                                         \
            int rB = w * 32 + s * 8 + srow8;                                  \
            __builtin_amdgcn_global_load_lds(                                 \
                (const __attribute__((address_space(1))) unsigned int*)       \
                    (gB + (size_t)rB * KT32 + (p) * 64 + lq * 8),             \
                (__attribute__((address_space(3))) unsigned int*)             \
                    (&Bs[buf][(w * 32 + s * 8) * 64]),                        \
                16, 0, 0);                                                    \
        }                                                                     \
    }

// One A-record per thread: row bl, logical quads jp*4..jp*4+3, swizzled.
#define GEN_AS(p, buf)                                                        \
    {                                                                         \
        int bl = t & 255, jp = t >> 8;                                        \
        int rx = bl & 7;                                                      \
        float xv = xt[((p) * 2 + jp) * 256 + bl];                             \
        float xc = fminf(fmaxf(xv, -1.f), 1.f);                               \
        float pos = fmaxf(xc, 0.f);                                           \
        float neg = xc - pos;                                                 \
        int k0; float Nv[5];                                                  \
        bspline5(xc, k0, Nv);                                                 \
        half_t* rb = &As[buf][bl * 64];                                       \
        half8 z8 = {};                                                        \
        _Pragma("unroll")                                                     \
        for (int kq = 0; kq < 4; ++kq)                                        \
            *(half8*)(rb + ((jp * 4 + kq) ^ rx) * 8) = z8;                    \
        *(unsigned*)(rb + ((jp * 4 + 2) ^ rx) * 8 + 4) = packh2(neg, pos);    \
        _Pragma("unroll")                                                     \
        for (int rr = 0; rr < 5; ++rr) {                                      \
            int k = k0 + rr;                                                  \
            if (k >= 0)                                                       \
                rb[(((jp * 4 + (k >> 3)) ^ rx) * 8) + (k & 7)] =              \
                    (half_t)Nv[rr];                                           \
        }                                                                     \
    }

    // ---- prologue: Bs[0] in flight; x-tile transposed into LDS; As[0] built.
    ISSUE_BS(0, 0)
#pragma unroll
    for (int v = 0; v < 4; ++v) {
        int r = v * 64 + (t >> 3);           // 0..255
        int cq = t & 7;                      // col-quad 0..7
        float4 xv4 = *(const float4*)(x + (size_t)(m0 + r) * J_DIM + j0 + cq * 4);
#pragma unroll
        for (int c = 0; c < 4; ++c)
            xt[(cq * 4 + c) * 256 + r] = ((const float*)&xv4)[c];
    }
    __syncthreads();                         // xt visible (also drains Bs[0])
    GEN_AS(0, 0)

    // ---- main loop: 16 phases of 2 j (K=64) each.
    for (int p = 0; p < NPH; ++p) {
        asm volatile("s_waitcnt vmcnt(0) lgkmcnt(0)" ::: "memory");
        __builtin_amdgcn_s_barrier();        // Bs[p] + As[p] ready; buf (p+1)&1 free

        if (p + 1 < NPH) ISSUE_BS(p + 1, (p + 1) & 1)

        const half_t* Ab = &As[p & 1][0];
        const half_t* Bb = &Bs[p & 1][0];
#pragma unroll
        for (int ks = 0; ks < 2; ++ks) {
            half8 af[8], bf[4];
#pragma unroll
            for (int nt = 0; nt < 4; ++nt)
                bf[nt] = *(const half8*)(Bb + (wn * 64 + nt * 16 + fr) * 64
                                            + (((ks * 4 + q) ^ (fr & 7)) * 8));
#pragma unroll
            for (int mt = 0; mt < 8; ++mt)
                af[mt] = *(const half8*)(Ab + (wm * 128 + mt * 16 + fr) * 64
                                            + (((ks * 4 + q) ^ (fr & 7)) * 8));
            __builtin_amdgcn_s_setprio(1);
#pragma unroll
            for (int mt = 0; mt < 8; ++mt)
#pragma unroll
                for (int nt = 0; nt < 4; ++nt)
                    acc[mt][nt] = __builtin_amdgcn_mfma_f32_16x16x32_f16(
                        af[mt], bf[nt], acc[mt][nt], 0, 0, 0);
            __builtin_amdgcn_s_setprio(0);
        }
        if (p + 1 < NPH) GEN_AS(p + 1, (p + 1) & 1)
    }
#undef GEN_AS
#undef ISSUE_BS

    // epilogue (R10-verified): C/D col = lane&15, row = (lane>>4)*4 + reg.
    float* dst = out + (size_t)bz * ((size_t)B_DIM * O_DIM);
#pragma unroll
    for (int mt = 0; mt < 8; ++mt)
#pragma unroll
        for (int nt = 0; nt < 4; ++nt) {
            int rw = m0 + wm * 128 + mt * 16 + q * 4;
            int cc = n0 + wn * 64 + nt * 16 + fr;
#pragma unroll
            for (int rg = 0; rg < 4; ++rg)
                dst[(size_t)(rw + rg) * O_DIM + cc] = acc[mt][nt][rg];
        }
}

// ---------------------------------------------------------------------------
// Sum the KSPLIT partial buffers into out. 71 MB traffic, BW-bound (~11 us).
__global__ __launch_bounds__(256) void reduce16(const float* __restrict__ parts,
                                                float* __restrict__ out) {
    constexpr int N4 = B_DIM * O_DIM / 4;
    int i = blockIdx.x * 256 + threadIdx.x;       // float4 index
    const float4* p = (const float4*)parts;
    float4 a = p[i];
#pragma unroll
    for (int z = 1; z < KSPLIT; ++z) {
        float4 b = p[(size_t)z * N4 + i];
        a.x += b.x; a.y += b.y; a.z += b.z; a.w += b.w;
    }
    ((float4*)out)[i] = a;
}

// ---------------------------------------------------------------------------
// Zero-workspace fallback (only if ws_size too small): correct but slow.
__global__ __launch_bounds__(256) void kan_fallback(const float* __restrict__ x,
                                                    const float* __restrict__ pw,
                                                    const float* __restrict__ bw,
                                                    const float* __restrict__ sw,
                                                    const float* __restrict__ sc,
                                                    float* __restrict__ out) {
    __shared__ float s_neg[J_DIM], s_pos[J_DIM], s_bas[J_DIM][5];
    __shared__ int s_k0[J_DIM];
    int b = blockIdx.x;
    int t = threadIdx.x;
#pragma unroll
    for (int jj = 0; jj < 2; ++jj) {
        int j = t + jj * 256;
        float xv = x[(size_t)b * J_DIM + j];
        float xc = fminf(fmaxf(xv, -1.f), 1.f);
        float pos = fmaxf(xc, 0.f);
        s_pos[j] = pos;
        s_neg[j] = xc - pos;
        int k0; float Nv[5];
        bspline5(xc, k0, Nv);
        s_k0[j] = k0;
#pragma unroll
        for (int r = 0; r < 5; ++r) s_bas[j][r] = Nv[r];
    }
    __syncthreads();
    for (int i = t; i < O_DIM; i += 256) {
        float acc = 0.f;
        for (int j = 0; j < J_DIM; ++j) {
            size_t ij = (size_t)i * J_DIM + j;
            float bwv = bw[ij];
            acc += bwv * (pw[ij] * s_neg[j] + s_pos[j]);
            int k0 = s_k0[j];
            const float* cp = sc + ij * 20;
            float sp = 0.f;
#pragma unroll
            for (int r = 0; r < 5; ++r) {
                int k = k0 + r;
                if (k >= 0) sp += s_bas[j][r] * cp[k];
            }
            acc += sw[ij] * sp;
        }
        out[(size_t)b * O_DIM + i] = acc;
    }
}

// ---------------------------------------------------------------------------
extern "C" void kernel_launch(void* const* d_in, const int* in_sizes, int n_in,
                              void* d_out, int out_size, void* d_ws, size_t ws_size,
                              hipStream_t stream) {
    const float* x  = (const float*)d_in[0];
    const float* pw = (const float*)d_in[1];
    const float* bw = (const float*)d_in[2];
    const float* sw = (const float*)d_in[3];
    const float* sc = (const float*)d_in[4];
    float* out = (float*)d_out;

    const size_t ct32_bytes  = (size_t)O_DIM * KT32 * sizeof(half_t);            // 16.8 MB
    const size_t parts_bytes = (size_t)KSPLIT * B_DIM * O_DIM * sizeof(float);   // 67.1 MB

    if (ws_size >= ct32_bytes + parts_bytes) {
        half_t* Ct32 = (half_t*)d_ws;
        float* parts = (float*)((char*)d_ws + ct32_bytes);   // 16B-aligned

        prep_c32<<<O_DIM / 2, 256, 0, stream>>>(pw, bw, sw, sc, Ct32);
        dim3 g(B_DIM / BM, O_DIM / BN, KSPLIT);              // (8, 2, 16)
        kan_fused<<<g, 512, 0, stream>>>(x, Ct32, parts);
        reduce16<<<(B_DIM * O_DIM / 4) / 256, 256, 0, stream>>>(parts, out);
    } else {
        kan_fallback<<<B_DIM, 256, 0, stream>>>(x, pw, bw, sw, sc, out);
    }
}

// Round 9
// 138.445 us; speedup vs baseline: 1.0703x; 1.0703x over previous
//
#include <hip/hip_runtime.h>

// KAN layer, R12. Records padded to 32 slots: A-side generated in-kernel from
// x; Ct32 materialized (16.8 MB). R11 decode: fusion worked (48.4 vs 40+40)
// but prep_c32 at 256 blocks = 1 wave/SIMD was latency-starved (~44 us), and
// kan_fused drained vmcnt(0)+lgkmcnt(0) every phase (T4 violation).
// R12 fixes:
//  (a) prep_c32: 1024 blocks, 1 record/thread (16 waves/CU TLP). 44 -> ~7.
//  (b) kan_fused: xt deleted (x -> 16 named regs, full 16-phase unroll for
//      static indexing); Bs 3-buffered (As 2x32K + Bs 3x32K = 160 KiB); DMA
//      2 phases ahead; loop-top counted vmcnt (4/5/6..6/5/4,4,4/0, never 0
//      until tail); lgkmcnt(0) only at phase end (GEN_AS visibility).
// ws: Ct32 16.8 MB + partials16 67.1 MB = 83.9 MB.

typedef _Float16 half_t;
typedef __attribute__((ext_vector_type(8))) _Float16 half8;
typedef __attribute__((ext_vector_type(4))) float floatx4;

#define B_DIM   2048
#define J_DIM   512
#define O_DIM   512
#define SLOT32  32
#define KT32    (J_DIM * SLOT32)     // 16384
#define BM      256
#define BN      256
#define KSPLIT  16

// ---------------------------------------------------------------------------
// Quartic B-spline local basis, uniform knots g_i = -1.5 + i*(3.125/24).
// (Reference quirk: linspace(-1.5, 1.625, 25) -> spacing 3.125/24, NOT 0.125.)
__device__ __forceinline__ void bspline5(float xc, int& k0, float Nv[5]) {
    const float invS = 7.68f;              // 24/3.125 (exact ratio)
    float u = (xc + 1.5f) * invS;          // knot units
    int m = (int)u;
    m = min(max(m, 3), 19);
    k0 = m - 4;
    Nv[0] = 1.f; Nv[1] = 0.f; Nv[2] = 0.f; Nv[3] = 0.f; Nv[4] = 0.f;
#pragma unroll
    for (int d = 1; d <= 4; ++d) {
        float nw[5];
        float inv_d = 1.0f / (float)d;
#pragma unroll
        for (int r = 0; r < 5; ++r) {
            if (r > d) { nw[r] = 0.f; continue; }
            float kk = (float)(m - d + r);
            float acc = 0.f;
            if (r >= 1) acc += (u - kk) * Nv[r - 1];
            if (r < d)  acc += (kk + (float)(d + 1) - u) * Nv[r];
            nw[r] = acc * inv_d;
        }
#pragma unroll
        for (int r = 0; r < 5; ++r) Nv[r] = nw[r];
    }
}

__device__ __forceinline__ unsigned packh2(float a, float b) {
    half_t ha = (half_t)a, hb = (half_t)b;    // RTN, identical to prior rounds
    unsigned short ua = __builtin_bit_cast(unsigned short, ha);
    unsigned short ub = __builtin_bit_cast(unsigned short, hb);
    return (unsigned)ua | ((unsigned)ub << 16);
}

// ---------------------------------------------------------------------------
// prep_c32 R12: 1024 blocks x 256 thr, ONE record per thread (16 waves/CU).
// block b: i = b>>1, j = ((b&1)<<8) + t. All-register build, 4 uint4 stores
// (lane-stride 64 B: 2 lanes per 128-B line, adequate at this TLP).
__global__ __launch_bounds__(256) void prep_c32(const float* __restrict__ pw,
                                                const float* __restrict__ bw,
                                                const float* __restrict__ sw,
                                                const float* __restrict__ sc,
                                                half_t* __restrict__ Ct) {
    int bid = blockIdx.x;
    int i = bid >> 1;
    int j = ((bid & 1) << 8) + threadIdx.x;
    size_t ij = (size_t)i * J_DIM + j;
    float s = sw[ij], b = bw[ij], p = pw[ij];
    const float4* sp4 = (const float4*)(sc + ij * 20);
    unsigned u[16];
#pragma unroll
    for (int v = 0; v < 5; ++v) {
        float4 c4 = sp4[v];
        u[v * 2 + 0] = packh2(s * c4.x, s * c4.y);
        u[v * 2 + 1] = packh2(s * c4.z, s * c4.w);
    }
    u[10] = packh2(b * p, b);
#pragma unroll
    for (int v = 11; v < 16; ++v) u[v] = 0u;
    uint4* dst = (uint4*)(Ct + (size_t)i * KT32 + (size_t)j * SLOT32);
#pragma unroll
    for (int v = 0; v < 4; ++v)
        dst[v] = make_uint4(u[4 * v], u[4 * v + 1], u[4 * v + 2], u[4 * v + 3]);
}

// ---------------------------------------------------------------------------
// kan_fused R12: grid (8,2,16) = 256 blocks (1/CU), 512 thr = 8 waves (2m x 4n),
// wave-tile 128x64, acc[8][4]. 16 phases (2 j = K=64 each), FULLY UNROLLED.
// Bs 3-buffered, DMA issued 2 phases ahead; per-phase FIFO-exact vmcnt.
// x: 16 values/thread in named registers (xv0..15), loads spread across
// phases 0..9 (counted in the vmcnt FIFO arithmetic below).
// Swizzle (R11-verified): physical quad q of row r holds logical quad q^(r&7)
// on both As (ds_write side) and Bs (pre-swizzled DMA source side).
__global__ __launch_bounds__(512, 2) void kan_fused(const float* __restrict__ x,
                                                    const half_t* __restrict__ Ct,
                                                    float* __restrict__ out) {
    __shared__ half_t As[2][BM * 64];      // 2 x 32 KB
    __shared__ half_t Bs[3][BN * 64];      // 3 x 32 KB  -> 160 KiB total

    int lid = blockIdx.x + 8 * (blockIdx.y + 2 * blockIdx.z);   // 0..255
    int c8 = lid & 7;                // XCD
    int r2 = lid >> 3;
    int bz = c8 + 8 * (r2 & 1);      // z in {c8, c8+8}
    int rr2 = r2 >> 1;
    int bx = rr2 & 7;                // 8 m-blocks
    int by = rr2 >> 3;               // 2 n-blocks

    int m0 = bx * BM;
    int n0 = by * BN;
    int j0 = bz * 32;                // this block's 32-j slice

    int t = threadIdx.x;
    int w = t >> 6, l = t & 63;
    int wm = w >> 2, wn = w & 3;     // wave grid 2 x 4
    int q = l >> 4, fr = l & 15;

    const half_t* gB = Ct + (size_t)n0 * KT32 + (size_t)j0 * SLOT32;
    int srow8 = l >> 3;                      // 0..7 row within 8-row group
    int lq    = (l & 7) ^ srow8;             // pre-swizzled source quad

    int bl = t & 255, jp = t >> 8;           // A-record owner coords
    const float* xb = x + (size_t)(m0 + bl) * J_DIM + j0 + jp;

    floatx4 acc[8][4] = {};

#define ISSUE_BS(p, buf)                                                      \
    {                                                                         \
        _Pragma("unroll")                                                     \
        for (int s = 0; s < 4; ++s) {                                         \
            int rB = w * 32 + s * 8 + srow8;                                  \
            __builtin_amdgcn_global_load_lds(                                 \
                (const __attribute__((address_space(1))) unsigned int*)       \
                    (gB + (size_t)rB * KT32 + (p) * 64 + lq * 8),             \
                (__attribute__((address_space(3))) unsigned int*)             \
                    (&Bs[buf][(w * 32 + s * 8) * 64]),                        \
                16, 0, 0);                                                    \
        }                                                                     \
    }

// Build one A-record (row bl, j = j0 + 2*phase + jp) into As[buf], swizzled.
#define GEN_AS(buf, XV)                                                       \
    {                                                                         \
        int rx = bl & 7;                                                      \
        float xcl = fminf(fmaxf((XV), -1.f), 1.f);                            \
        float pos = fmaxf(xcl, 0.f);                                          \
        float neg = xcl - pos;                                                \
        int k0; float Nv[5];                                                  \
        bspline5(xcl, k0, Nv);                                                \
        half_t* rb = &As[buf][bl * 64];                                       \
        half8 z8 = {};                                                        \
        _Pragma("unroll")                                                     \
        for (int kq = 0; kq < 4; ++kq)                                        \
            *(half8*)(rb + ((jp * 4 + kq) ^ rx) * 8) = z8;                    \
        *(unsigned*)(rb + ((jp * 4 + 2) ^ rx) * 8 + 4) = packh2(neg, pos);    \
        _Pragma("unroll")                                                     \
        for (int rr = 0; rr < 5; ++rr) {                                      \
            int k = k0 + rr;                                                  \
            if (k >= 0)                                                       \
                rb[(((jp * 4 + (k >> 3)) ^ rx) * 8) + (k & 7)] =              \
                    (half_t)Nv[rr];                                           \
        }                                                                     \
    }

#define MMPH(apar, bsi)                                                       \
    {                                                                         \
        const half_t* Ab = &As[apar][0];                                      \
        const half_t* Bb = &Bs[bsi][0];                                       \
        _Pragma("unroll")                                                     \
        for (int ks = 0; ks < 2; ++ks) {                                      \
            half8 af[8], bf[4];                                               \
            _Pragma("unroll")                                                 \
            for (int nt = 0; nt < 4; ++nt)                                    \
                bf[nt] = *(const half8*)(Bb + (wn * 64 + nt * 16 + fr) * 64   \
                                            + (((ks * 4 + q) ^ (fr & 7)) * 8));\
            _Pragma("unroll")                                                 \
            for (int mt = 0; mt < 8; ++mt)                                    \
                af[mt] = *(const half8*)(Ab + (wm * 128 + mt * 16 + fr) * 64  \
                                            + (((ks * 4 + q) ^ (fr & 7)) * 8));\
            __builtin_amdgcn_s_setprio(1);                                    \
            _Pragma("unroll")                                                 \
            for (int mt = 0; mt < 8; ++mt)                                    \
                _Pragma("unroll")                                             \
                for (int nt = 0; nt < 4; ++nt)                                \
                    acc[mt][nt] = __builtin_amdgcn_mfma_f32_16x16x32_f16(     \
                        af[mt], bf[nt], acc[mt][nt], 0, 0, 0);                \
            __builtin_amdgcn_s_setprio(0);                                    \
        }                                                                     \
    }

#define PWAIT(VN)                                                             \
    asm volatile("s_waitcnt vmcnt(" #VN ")" ::: "memory");                    \
    __builtin_amdgcn_s_barrier();
#define LGKM0 asm volatile("s_waitcnt lgkmcnt(0)" ::: "memory");

    // ---- prologue: x for phases 0..5; Bs0, Bs1 in flight; As[0] built.
    float xv0 = xb[0],  xv1 = xb[2],  xv2 = xb[4];
    float xv3 = xb[6],  xv4 = xb[8],  xv5 = xb[10];
    float xv6, xv7, xv8, xv9, xv10, xv11, xv12, xv13, xv14, xv15;
    ISSUE_BS(0, 0)
    ISSUE_BS(1, 1)
    GEN_AS(0, xv0)          // compiler auto-waits xv0
    LGKM0

    // ---- 16 phases, fully unrolled. Per-phase: PWAIT(FIFO-exact N);
    // issue Bs[p+2]; issue x for phase p+6 (p<=9); MFMA; GEN_AS(p+1); LGKM0.
    PWAIT(4)  ISSUE_BS(2, 2)   xv6  = xb[12]; MMPH(0, 0) GEN_AS(1, xv1)  LGKM0  // p0
    PWAIT(5)  ISSUE_BS(3, 0)   xv7  = xb[14]; MMPH(1, 1) GEN_AS(0, xv2)  LGKM0  // p1
    PWAIT(6)  ISSUE_BS(4, 1)   xv8  = xb[16]; MMPH(0, 2) GEN_AS(1, xv3)  LGKM0  // p2
    PWAIT(6)  ISSUE_BS(5, 2)   xv9  = xb[18]; MMPH(1, 0) GEN_AS(0, xv4)  LGKM0  // p3
    PWAIT(6)  ISSUE_BS(6, 0)   xv10 = xb[20]; MMPH(0, 1) GEN_AS(1, xv5)  LGKM0  // p4
    PWAIT(6)  ISSUE_BS(7, 1)   xv11 = xb[22]; MMPH(1, 2) GEN_AS(0, xv6)  LGKM0  // p5
    PWAIT(6)  ISSUE_BS(8, 2)   xv12 = xb[24]; MMPH(0, 0) GEN_AS(1, xv7)  LGKM0  // p6
    PWAIT(6)  ISSUE_BS(9, 0)   xv13 = xb[26]; MMPH(1, 1) GEN_AS(0, xv8)  LGKM0  // p7
    PWAIT(6)  ISSUE_BS(10, 1)  xv14 = xb[28]; MMPH(0, 2) GEN_AS(1, xv9)  LGKM0  // p8
    PWAIT(6)  ISSUE_BS(11, 2)  xv15 = xb[30]; MMPH(1, 0) GEN_AS(0, xv10) LGKM0  // p9
    PWAIT(6)  ISSUE_BS(12, 0)                 MMPH(0, 1) GEN_AS(1, xv11) LGKM0  // p10
    PWAIT(5)  ISSUE_BS(13, 1)                 MMPH(1, 2) GEN_AS(0, xv12) LGKM0  // p11
    PWAIT(4)  ISSUE_BS(14, 2)                 MMPH(0, 0) GEN_AS(1, xv13) LGKM0  // p12
    PWAIT(4)  ISSUE_BS(15, 0)                 MMPH(1, 1) GEN_AS(0, xv14) LGKM0  // p13
    PWAIT(4)                                  MMPH(0, 2) GEN_AS(1, xv15) LGKM0  // p14
    PWAIT(0)                                  MMPH(1, 0)                        // p15

#undef PWAIT
#undef LGKM0
#undef MMPH
#undef GEN_AS
#undef ISSUE_BS

    // epilogue (verified): C/D col = lane&15, row = (lane>>4)*4 + reg.
    float* dst = out + (size_t)bz * ((size_t)B_DIM * O_DIM);
#pragma unroll
    for (int mt = 0; mt < 8; ++mt)
#pragma unroll
        for (int nt = 0; nt < 4; ++nt) {
            int rw = m0 + wm * 128 + mt * 16 + q * 4;
            int cc = n0 + wn * 64 + nt * 16 + fr;
#pragma unroll
            for (int rg = 0; rg < 4; ++rg)
                dst[(size_t)(rw + rg) * O_DIM + cc] = acc[mt][nt][rg];
        }
}

// ---------------------------------------------------------------------------
// Sum the KSPLIT partial buffers into out. 71 MB traffic, BW-bound.
__global__ __launch_bounds__(256) void reduce16(const float* __restrict__ parts,
                                                float* __restrict__ out) {
    constexpr int N4 = B_DIM * O_DIM / 4;
    int i = blockIdx.x * 256 + threadIdx.x;       // float4 index
    const float4* p = (const float4*)parts;
    float4 a = p[i];
#pragma unroll
    for (int z = 1; z < KSPLIT; ++z) {
        float4 b = p[(size_t)z * N4 + i];
        a.x += b.x; a.y += b.y; a.z += b.z; a.w += b.w;
    }
    ((float4*)out)[i] = a;
}

// ---------------------------------------------------------------------------
// Zero-workspace fallback (only if ws_size too small): correct but slow.
__global__ __launch_bounds__(256) void kan_fallback(const float* __restrict__ x,
                                                    const float* __restrict__ pw,
                                                    const float* __restrict__ bw,
                                                    const float* __restrict__ sw,
                                                    const float* __restrict__ sc,
                                                    float* __restrict__ out) {
    __shared__ float s_neg[J_DIM], s_pos[J_DIM], s_bas[J_DIM][5];
    __shared__ int s_k0[J_DIM];
    int b = blockIdx.x;
    int t = threadIdx.x;
#pragma unroll
    for (int jj = 0; jj < 2; ++jj) {
        int j = t + jj * 256;
        float xv = x[(size_t)b * J_DIM + j];
        float xc = fminf(fmaxf(xv, -1.f), 1.f);
        float pos = fmaxf(xc, 0.f);
        s_pos[j] = pos;
        s_neg[j] = xc - pos;
        int k0; float Nv[5];
        bspline5(xc, k0, Nv);
        s_k0[j] = k0;
#pragma unroll
        for (int r = 0; r < 5; ++r) s_bas[j][r] = Nv[r];
    }
    __syncthreads();
    for (int i = t; i < O_DIM; i += 256) {
        float acc = 0.f;
        for (int j = 0; j < J_DIM; ++j) {
            size_t ij = (size_t)i * J_DIM + j;
            float bwv = bw[ij];
            acc += bwv * (pw[ij] * s_neg[j] + s_pos[j]);
            int k0 = s_k0[j];
            const float* cp = sc + ij * 20;
            float sp = 0.f;
#pragma unroll
            for (int r = 0; r < 5; ++r) {
                int k = k0 + r;
                if (k >= 0) sp += s_bas[j][r] * cp[k];
            }
            acc += sw[ij] * sp;
        }
        out[(size_t)b * O_DIM + i] = acc;
    }
}

// ---------------------------------------------------------------------------
extern "C" void kernel_launch(void* const* d_in, const int* in_sizes, int n_in,
                              void* d_out, int out_size, void* d_ws, size_t ws_size,
                              hipStream_t stream) {
    const float* x  = (const float*)d_in[0];
    const float* pw = (const float*)d_in[1];
    const float* bw = (const float*)d_in[2];
    const float* sw = (const float*)d_in[3];
    const float* sc = (const float*)d_in[4];
    float* out = (float*)d_out;

    const size_t ct32_bytes  = (size_t)O_DIM * KT32 * sizeof(half_t);            // 16.8 MB
    const size_t parts_bytes = (size_t)KSPLIT * B_DIM * O_DIM * sizeof(float);   // 67.1 MB

    if (ws_size >= ct32_bytes + parts_bytes) {
        half_t* Ct32 = (half_t*)d_ws;
        float* parts = (float*)((char*)d_ws + ct32_bytes);   // 16B-aligned

        prep_c32<<<O_DIM * 2, 256, 0, stream>>>(pw, bw, sw, sc, Ct32);
        dim3 g(B_DIM / BM, O_DIM / BN, KSPLIT);              // (8, 2, 16)
        kan_fused<<<g, 512, 0, stream>>>(x, Ct32, parts);
        reduce16<<<(B_DIM * O_DIM / 4) / 256, 256, 0, stream>>>(parts, out);
    } else {
        kan_fallback<<<B_DIM, 256, 0, stream>>>(x, pw, bw, sw, sc, out);
    }
}

// Round 11
// 137.300 us; speedup vs baseline: 1.0792x; 1.0083x over previous
//
#include <hip/hip_runtime.h>

// KAN layer, R13b: RESUBMIT of R13 (bench was an infra failure — container
// acquisition died twice; no measurement taken). Recombination of the two
// proven components:
//   - kan_fused: R11 version VERBATIM (measured 48.4 us, MfmaUtil 26.5%).
//     R12's counted-vmcnt graft regressed it to 67-73 (both pipes LESS busy:
//     hand-pinned FIFO + scalar-x-loads entangled in vmcnt + 16x unroll beat
//     the compiler's own schedule). Simple drain-per-phase wins on this
//     1-block/CU lockstep structure.
//   - prep_c32: R12 version VERBATIM (1024 blocks, 1 record/thread, 16
//     waves/CU; decode-proven ~7 us vs R11's 44 at 1 wave/SIMD).
// Structure: records padded to 32 slots; A-side generated in-kernel from x
// (fusion win: prep_A+gemm 80 -> 48); Ct32 materialized 16.8 MB; KSPLIT=16
// j-slices -> fp32 partials + reduce16.
// ws: Ct32 16.8 MB + partials16 67.1 MB = 83.9 MB.

typedef _Float16 half_t;
typedef __attribute__((ext_vector_type(8))) _Float16 half8;
typedef __attribute__((ext_vector_type(4))) float floatx4;

#define B_DIM   2048
#define J_DIM   512
#define O_DIM   512
#define SLOT32  32
#define KT32    (J_DIM * SLOT32)     // 16384
#define BM      256
#define BN      256
#define KSPLIT  16                   // j-slice = 32 j = 16 phases of 2 j
#define NPH     16

// ---------------------------------------------------------------------------
// Quartic B-spline local basis, uniform knots g_i = -1.5 + i*(3.125/24).
// (Reference quirk: linspace(-1.5, 1.625, 25) -> spacing 3.125/24, NOT 0.125.)
__device__ __forceinline__ void bspline5(float xc, int& k0, float Nv[5]) {
    const float invS = 7.68f;              // 24/3.125 (exact ratio)
    float u = (xc + 1.5f) * invS;          // knot units
    int m = (int)u;
    m = min(max(m, 3), 19);
    k0 = m - 4;
    Nv[0] = 1.f; Nv[1] = 0.f; Nv[2] = 0.f; Nv[3] = 0.f; Nv[4] = 0.f;
#pragma unroll
    for (int d = 1; d <= 4; ++d) {
        float nw[5];
        float inv_d = 1.0f / (float)d;
#pragma unroll
        for (int r = 0; r < 5; ++r) {
            if (r > d) { nw[r] = 0.f; continue; }
            float kk = (float)(m - d + r);
            float acc = 0.f;
            if (r >= 1) acc += (u - kk) * Nv[r - 1];
            if (r < d)  acc += (kk + (float)(d + 1) - u) * Nv[r];
            nw[r] = acc * inv_d;
        }
#pragma unroll
        for (int r = 0; r < 5; ++r) Nv[r] = nw[r];
    }
}

__device__ __forceinline__ unsigned packh2(float a, float b) {
    half_t ha = (half_t)a, hb = (half_t)b;    // RTN, identical to prior rounds
    unsigned short ua = __builtin_bit_cast(unsigned short, ha);
    unsigned short ub = __builtin_bit_cast(unsigned short, hb);
    return (unsigned)ua | ((unsigned)ub << 16);
}

// ---------------------------------------------------------------------------
// prep_c32 (R12-proven): 1024 blocks x 256 thr, ONE record per thread
// (16 waves/CU TLP). block b: i = b>>1, j = ((b&1)<<8) + t. All-register
// build, 4 uint4 stores.
__global__ __launch_bounds__(256) void prep_c32(const float* __restrict__ pw,
                                                const float* __restrict__ bw,
                                                const float* __restrict__ sw,
                                                const float* __restrict__ sc,
                                                half_t* __restrict__ Ct) {
    int bid = blockIdx.x;
    int i = bid >> 1;
    int j = ((bid & 1) << 8) + threadIdx.x;
    size_t ij = (size_t)i * J_DIM + j;
    float s = sw[ij], b = bw[ij], p = pw[ij];
    const float4* sp4 = (const float4*)(sc + ij * 20);
    unsigned u[16];
#pragma unroll
    for (int v = 0; v < 5; ++v) {
        float4 c4 = sp4[v];
        u[v * 2 + 0] = packh2(s * c4.x, s * c4.y);
        u[v * 2 + 1] = packh2(s * c4.z, s * c4.w);
    }
    u[10] = packh2(b * p, b);
#pragma unroll
    for (int v = 11; v < 16; ++v) u[v] = 0u;
    uint4* dst = (uint4*)(Ct + (size_t)i * KT32 + (size_t)j * SLOT32);
#pragma unroll
    for (int v = 0; v < 4; ++v)
        dst[v] = make_uint4(u[4 * v], u[4 * v + 1], u[4 * v + 2], u[4 * v + 3]);
}

// ---------------------------------------------------------------------------
// kan_fused (R11-proven, 48.4 us): grid (8,2,16) = 256 blocks (1/CU), 512 thr
// = 8 waves (2m x 4n), wave-tile 128x64, acc[8][4]. Per phase (2 j, K=64):
// stage Bs[p+1] via global_load_lds (pre-swizzled source, rule-21 involution),
// GEN 512 A-records (bspline5 + swizzled ds_write, row-XOR (r&7) on 128-B
// rows), 2x32 MFMA. LDS = 32K xt + 2x32K As + 2x32K Bs = 160 KiB.
// Simple per-phase drain (vmcnt(0)+lgkmcnt(0)) — measured better than every
// counted-vmcnt graft tried on this structure (R12: -20 us).
__global__ __launch_bounds__(512, 2) void kan_fused(const float* __restrict__ x,
                                                    const half_t* __restrict__ Ct,
                                                    float* __restrict__ out) {
    __shared__ float  xt[32 * 256];        // x-tile, TRANSPOSED [col][b], 32 KB
    __shared__ half_t As[2][BM * 64];      // 2 x 32 KB
    __shared__ half_t Bs[2][BN * 64];      // 2 x 32 KB   -> 160 KiB total

    int lid = blockIdx.x + 8 * (blockIdx.y + 2 * blockIdx.z);   // 0..255
    int c8 = lid & 7;                // XCD
    int r2 = lid >> 3;
    int bz = c8 + 8 * (r2 & 1);      // z in {c8, c8+8}
    int rr2 = r2 >> 1;
    int bx = rr2 & 7;                // 8 m-blocks
    int by = rr2 >> 3;               // 2 n-blocks

    int m0 = bx * BM;
    int n0 = by * BN;
    int j0 = bz * 32;                // this block's 32-j slice

    int t = threadIdx.x;
    int w = t >> 6, l = t & 63;
    int wm = w >> 2, wn = w & 3;     // wave grid 2 x 4
    int q = l >> 4, fr = l & 15;

    const half_t* gB = Ct + (size_t)n0 * KT32 + (size_t)j0 * SLOT32;

    // Bs staging decomposition: per load, wave covers 8 rows x 8 quads (1 KB).
    int srow8 = l >> 3;                      // 0..7 row within 8-row group
    int lq    = (l & 7) ^ (srow8 & 7);       // logical quad at this lane's dest

    floatx4 acc[8][4] = {};

// 4 loads/thread/phase; dest linear (DMA), source pre-swizzled.
#define ISSUE_BS(p, buf)                                                      \
    {                                                                         \
        _Pragma("unroll")                                                     \
        for (int s = 0; s < 4; ++s) {                                         \
            int rB = w * 32 + s * 8 + srow8;                                  \
            __builtin_amdgcn_global_load_lds(                                 \
                (const __attribute__((address_space(1))) unsigned int*)       \
                    (gB + (size_t)rB * KT32 + (p) * 64 + lq * 8),             \
                (__attribute__((address_space(3))) unsigned int*)             \
                    (&Bs[buf][(w * 32 + s * 8) * 64]),                        \
                16, 0, 0);                                                    \
        }                                                                     \
    }

// One A-record per thread: row bl, logical quads jp*4..jp*4+3, swizzled.
#define GEN_AS(p, buf)                                                        \
    {                                                                         \
        int bl = t & 255, jp = t >> 8;                                        \
        int rx = bl & 7;                                                      \
        float xv = xt[((p) * 2 + jp) * 256 + bl];                             \
        float xc = fminf(fmaxf(xv, -1.f), 1.f);                               \
        float pos = fmaxf(xc, 0.f);                                           \
        float neg = xc - pos;                                                 \
        int k0; float Nv[5];                                                  \
        bspline5(xc, k0, Nv);                                                 \
        half_t* rb = &As[buf][bl * 64];                                       \
        half8 z8 = {};                                                        \
        _Pragma("unroll")                                                     \
        for (int kq = 0; kq < 4; ++kq)                                        \
            *(half8*)(rb + ((jp * 4 + kq) ^ rx) * 8) = z8;                    \
        *(unsigned*)(rb + ((jp * 4 + 2) ^ rx) * 8 + 4) = packh2(neg, pos);    \
        _Pragma("unroll")                                                     \
        for (int rr = 0; rr < 5; ++rr) {                                      \
            int k = k0 + rr;                                                  \
            if (k >= 0)                                                       \
                rb[(((jp * 4 + (k >> 3)) ^ rx) * 8) + (k & 7)] =              \
                    (half_t)Nv[rr];                                           \
        }                                                                     \
    }

    // ---- prologue: Bs[0] in flight; x-tile transposed into LDS; As[0] built.
    ISSUE_BS(0, 0)
#pragma unroll
    for (int v = 0; v < 4; ++v) {
        int r = v * 64 + (t >> 3);           // 0..255
        int cq = t & 7;                      // col-quad 0..7
        float4 xv4 = *(const float4*)(x + (size_t)(m0 + r) * J_DIM + j0 + cq * 4);
#pragma unroll
        for (int c = 0; c < 4; ++c)
            xt[(cq * 4 + c) * 256 + r] = ((const float*)&xv4)[c];
    }
    __syncthreads();                         // xt visible (also drains Bs[0])
    GEN_AS(0, 0)

    // ---- main loop: 16 phases of 2 j (K=64) each.
    for (int p = 0; p < NPH; ++p) {
        asm volatile("s_waitcnt vmcnt(0) lgkmcnt(0)" ::: "memory");
        __builtin_amdgcn_s_barrier();        // Bs[p] + As[p] ready; buf (p+1)&1 free

        if (p + 1 < NPH) ISSUE_BS(p + 1, (p + 1) & 1)

        const half_t* Ab = &As[p & 1][0];
        const half_t* Bb = &Bs[p & 1][0];
#pragma unroll
        for (int ks = 0; ks < 2; ++ks) {
            half8 af[8], bf[4];
#pragma unroll
            for (int nt = 0; nt < 4; ++nt)
                bf[nt] = *(const half8*)(Bb + (wn * 64 + nt * 16 + fr) * 64
                                            + (((ks * 4 + q) ^ (fr & 7)) * 8));
#pragma unroll
            for (int mt = 0; mt < 8; ++mt)
                af[mt] = *(const half8*)(Ab + (wm * 128 + mt * 16 + fr) * 64
                                            + (((ks * 4 + q) ^ (fr & 7)) * 8));
            __builtin_amdgcn_s_setprio(1);
#pragma unroll
            for (int mt = 0; mt < 8; ++mt)
#pragma unroll
                for (int nt = 0; nt < 4; ++nt)
                    acc[mt][nt] = __builtin_amdgcn_mfma_f32_16x16x32_f16(
                        af[mt], bf[nt], acc[mt][nt], 0, 0, 0);
            __builtin_amdgcn_s_setprio(0);
        }
        if (p + 1 < NPH) GEN_AS(p + 1, (p + 1) & 1)
    }
#undef GEN_AS
#undef ISSUE_BS

    // epilogue (verified): C/D col = lane&15, row = (lane>>4)*4 + reg.
    float* dst = out + (size_t)bz * ((size_t)B_DIM * O_DIM);
#pragma unroll
    for (int mt = 0; mt < 8; ++mt)
#pragma unroll
        for (int nt = 0; nt < 4; ++nt) {
            int rw = m0 + wm * 128 + mt * 16 + q * 4;
            int cc = n0 + wn * 64 + nt * 16 + fr;
#pragma unroll
            for (int rg = 0; rg < 4; ++rg)
                dst[(size_t)(rw + rg) * O_DIM + cc] = acc[mt][nt][rg];
        }
}

// ---------------------------------------------------------------------------
// Sum the KSPLIT partial buffers into out. 71 MB traffic, BW-bound.
__global__ __launch_bounds__(256) void reduce16(const float* __restrict__ parts,
                                                float* __restrict__ out) {
    constexpr int N4 = B_DIM * O_DIM / 4;
    int i = blockIdx.x * 256 + threadIdx.x;       // float4 index
    const float4* p = (const float4*)parts;
    float4 a = p[i];
#pragma unroll
    for (int z = 1; z < KSPLIT; ++z) {
        float4 b = p[(size_t)z * N4 + i];
        a.x += b.x; a.y += b.y; a.z += b.z; a.w += b.w;
    }
    ((float4*)out)[i] = a;
}

// ---------------------------------------------------------------------------
// Zero-workspace fallback (only if ws_size too small): correct but slow.
__global__ __launch_bounds__(256) void kan_fallback(const float* __restrict__ x,
                                                    const float* __restrict__ pw,
                                                    const float* __restrict__ bw,
                                                    const float* __restrict__ sw,
                                                    const float* __restrict__ sc,
                                                    float* __restrict__ out) {
    __shared__ float s_neg[J_DIM], s_pos[J_DIM], s_bas[J_DIM][5];
    __shared__ int s_k0[J_DIM];
    int b = blockIdx.x;
    int t = threadIdx.x;
#pragma unroll
    for (int jj = 0; jj < 2; ++jj) {
        int j = t + jj * 256;
        float xv = x[(size_t)b * J_DIM + j];
        float xc = fminf(fmaxf(xv, -1.f), 1.f);
        float pos = fmaxf(xc, 0.f);
        s_pos[j] = pos;
        s_neg[j] = xc - pos;
        int k0; float Nv[5];
        bspline5(xc, k0, Nv);
        s_k0[j] = k0;
#pragma unroll
        for (int r = 0; r < 5; ++r) s_bas[j][r] = Nv[r];
    }
    __syncthreads();
    for (int i = t; i < O_DIM; i += 256) {
        float acc = 0.f;
        for (int j = 0; j < J_DIM; ++j) {
            size_t ij = (size_t)i * J_DIM + j;
            float bwv = bw[ij];
            acc += bwv * (pw[ij] * s_neg[j] + s_pos[j]);
            int k0 = s_k0[j];
            const float* cp = sc + ij * 20;
            float sp = 0.f;
#pragma unroll
            for (int r = 0; r < 5; ++r) {
                int k = k0 + r;
                if (k >= 0) sp += s_bas[j][r] * cp[k];
            }
            acc += sw[ij] * sp;
        }
        out[(size_t)b * O_DIM + i] = acc;
    }
}

// ---------------------------------------------------------------------------
extern "C" void kernel_launch(void* const* d_in, const int* in_sizes, int n_in,
                              void* d_out, int out_size, void* d_ws, size_t ws_size,
                              hipStream_t stream) {
    const float* x  = (const float*)d_in[0];
    const float* pw = (const float*)d_in[1];
    const float* bw = (const float*)d_in[2];
    const float* sw = (const float*)d_in[3];
    const float* sc = (const float*)d_in[4];
    float* out = (float*)d_out;

    const size_t ct32_bytes  = (size_t)O_DIM * KT32 * sizeof(half_t);            // 16.8 MB
    const size_t parts_bytes = (size_t)KSPLIT * B_DIM * O_DIM * sizeof(float);   // 67.1 MB

    if (ws_size >= ct32_bytes + parts_bytes) {
        half_t* Ct32 = (half_t*)d_ws;
        float* parts = (float*)((char*)d_ws + ct32_bytes);   // 16B-aligned

        prep_c32<<<O_DIM * 2, 256, 0, stream>>>(pw, bw, sw, sc, Ct32);
        dim3 g(B_DIM / BM, O_DIM / BN, KSPLIT);              // (8, 2, 16)
        kan_fused<<<g, 512, 0, stream>>>(x, Ct32, parts);
        reduce16<<<(B_DIM * O_DIM / 4) / 256, 256, 0, stream>>>(parts, out);
    } else {
        kan_fallback<<<B_DIM, 256, 0, stream>>>(x, pw, bw, sw, sc, out);
    }
}